// Round 4
// baseline (588.002 us; speedup 1.0000x reference)
//
#include <hip/hip_runtime.h>
#include <math.h>

// Problem constants (fixed by setup_inputs)
#define BD   1024            // batch B
#define LW   80              // walk length L
#define AA   76              // anchors A = L - w + 1, w = 5
#define NEGS 4               // negatives per anchor
#define D    128             // embed dim
#define PAIRS (BD * AA)      // 77824 (b,a) pairs
#define CHUNKS 4             // 19-anchor chunks per batch row
#define NBLOCKS (BD * CHUNKS) // 4096 blocks, 128 threads (2 waves) each

// Numerically-stable softplus matching jax.nn.softplus
__device__ __forceinline__ float softplus(float x) {
    return fmaxf(x, 0.0f) + log1pf(__expf(-fabsf(x)));
}

__device__ __forceinline__ float dot4(float4 a, float4 b) {
    return fmaf(a.x, b.x, fmaf(a.y, b.y, fmaf(a.z, b.z, a.w * b.w)));
}

// c ? a : b, componentwise (v_cndmask x4 off a precomputed vcc)
__device__ __forceinline__ float4 sel4(bool c, float4 a, float4 b) {
    float4 r;
    r.x = c ? a.x : b.x;  r.y = c ? a.y : b.y;
    r.z = c ? a.z : b.z;  r.w = c ? a.w : b.w;
    return r;
}

// swap halves of the wave (lane ^ 32), componentwise
__device__ __forceinline__ float4 swap32(float4 v) {
    float4 r;
    r.x = __shfl_xor(v.x, 32);  r.y = __shfl_xor(v.y, 32);
    r.z = __shfl_xor(v.z, 32);  r.w = __shfl_xor(v.w, 32);
    return r;
}

// Paired-row gather: lanes 0-31 get row i0, lanes 32-63 get row i1.
// One global_load_dwordx4 per lane = 1 KB per wave-load (2 embed rows).
__device__ __forceinline__ float4 pload(const float* ebase, bool half, int i0, int i1) {
    const int idx = half ? i1 : i0;
    return *(const float4*)(ebase + (size_t)idx * D);
}

// TLP experiment: 2 waves per 19-anchor chunk (wave0: anchors 0-9, wave1: 10-18),
// 128-thread blocks, 24 waves/CU resident (vs 16 before), half-length serial chains.
__global__ __launch_bounds__(128, 6) void sg_partial(
    const int* __restrict__ walk, const int* __restrict__ neg,
    const float* __restrict__ embed, float* __restrict__ ws)
{
    __shared__ float s_wsum[2];
    const int tid  = threadIdx.x;
    const int lane = tid & 63;
    const int l32  = lane & 31;
    const bool half = lane >= 32;           // which 32-lane half owns this fragment
    const int wave = __builtin_amdgcn_readfirstlane(tid >> 6);   // 0 or 1
    const int b     = blockIdx.x >> 2;
    const int chunk = blockIdx.x & 3;
    const int a0    = chunk * 19;

    const float* ebase = embed + l32 * 4;   // this lane's float4 slot within a row
    const int*   wrow  = walk + b * LW + a0;                  // wave-uniform
    const int*   nrow  = neg + (size_t)(b * AA + a0) * NEGS;  // wave-uniform

    const bool hi1 = lane & 1;
    const bool hi2 = lane & 2;
    const bool hi3 = lane & 4;

    float wsum = 0.0f;   // double-step logits (replication x4 per logit)
    float tsum = 0.0f;   // tail logits (replication x8 per logit), wave1 only

    // One double-step: anchors (even,odd) held in w01; window rows in w01..w45;
    // 8 negs of the two anchors in n01..n67. Produces 16 logits, 4x replicated.
    auto dstep = [&](float4 w01, float4 w23, float4 w45,
                     float4 n01, float4 n23, float4 n45, float4 n67) {
        const float4 Y   = swap32(w01);
        const float4 Z0  = sel4(half, Y, w01);     // even anchor's frag
        const float4 Z1  = sel4(half, w01, Y);     // odd anchor's frag
        const float4 Aop = sel4(half, w01, w23);   // pos row (odd | even+2) per half
        const float4 Bop = sel4(half, w23, w45);   // pos row (odd+2 | even+4) per half

        const float a0v = dot4(Z0, Aop);
        const float a1v = dot4(Z0, Bop);
        const float a2v = dot4(Z1, w23);
        const float a3v = dot4(Z1, w45);
        const float a4v = dot4(Z0, n01);
        const float a5v = dot4(Z0, n23);
        const float a6v = dot4(Z1, n45);
        const float a7v = dot4(Z1, n67);

        // reduce-scatter butterfly within each 32-lane half: 9 shuffles.
        float b0 = (hi1 ? a4v : a0v) + __shfl_xor(hi1 ? a0v : a4v, 1);
        float b1 = (hi1 ? a5v : a1v) + __shfl_xor(hi1 ? a1v : a5v, 1);
        float b2 = (hi1 ? a6v : a2v) + __shfl_xor(hi1 ? a2v : a6v, 1);
        float b3 = (hi1 ? a7v : a3v) + __shfl_xor(hi1 ? a3v : a7v, 1);

        float c0 = (hi2 ? b2 : b0) + __shfl_xor(hi2 ? b0 : b2, 2);
        float c1 = (hi2 ? b3 : b1) + __shfl_xor(hi2 ? b1 : b3, 2);

        float dv = (hi3 ? c1 : c0) + __shfl_xor(hi3 ? c0 : c1, 4);
        dv += __shfl_xor(dv, 8);
        dv += __shfl_xor(dv, 16);
        // dv = fully-reduced logit (4x replicated per half). neg iff bit0.
        wsum += softplus(hi1 ? dv : -dv);
    };

    if (wave == 0) {
        // ---- anchors a0+0 .. a0+9: 5 double-steps, window rows 0..13 ----
        float4 w01 = pload(ebase, half, wrow[0], wrow[1]);
        float4 w23 = pload(ebase, half, wrow[2], wrow[3]);
        float4 w45 = pload(ebase, half, wrow[4], wrow[5]);
        const int4 nva = *(const int4*)(nrow);
        const int4 nvb = *(const int4*)(nrow + 4);
        float4 n01 = pload(ebase, half, nva.x, nva.y);
        float4 n23 = pload(ebase, half, nva.z, nva.w);
        float4 n45 = pload(ebase, half, nvb.x, nvb.y);
        float4 n67 = pload(ebase, half, nvb.z, nvb.w);

        #pragma unroll
        for (int d = 0; d < 5; ++d) {
            float4 nw, m01, m23, m45, m67;
            if (d < 4) {   // prefetch next double-step
                nw = pload(ebase, half, wrow[2*d + 6], wrow[2*d + 7]);
                const int4 pa = *(const int4*)(nrow + 8*(d + 1));
                const int4 pb = *(const int4*)(nrow + 8*(d + 1) + 4);
                m01 = pload(ebase, half, pa.x, pa.y);
                m23 = pload(ebase, half, pa.z, pa.w);
                m45 = pload(ebase, half, pb.x, pb.y);
                m67 = pload(ebase, half, pb.z, pb.w);
            }
            dstep(w01, w23, w45, n01, n23, n45, n67);
            if (d < 4) {
                w01 = w23;  w23 = w45;  w45 = nw;
                n01 = m01;  n23 = m23;  n45 = m45;  n67 = m67;
            }
        }
    } else {
        // ---- anchors a0+10 .. a0+17 (4 double-steps) + tail anchor a0+18 ----
        const int* wr = wrow + 10;    // local window rows 10..22
        const int* nr = nrow + 40;    // negs of anchor 10 onward (16B-aligned)
        float4 w01 = pload(ebase, half, wr[0], wr[1]);
        float4 w23 = pload(ebase, half, wr[2], wr[3]);
        float4 w45 = pload(ebase, half, wr[4], wr[5]);
        const int4 nva = *(const int4*)(nr);
        const int4 nvb = *(const int4*)(nr + 4);
        float4 n01 = pload(ebase, half, nva.x, nva.y);
        float4 n23 = pload(ebase, half, nva.z, nva.w);
        float4 n45 = pload(ebase, half, nvb.x, nvb.y);
        float4 n67 = pload(ebase, half, nvb.z, nvb.w);

        #pragma unroll
        for (int d = 0; d < 4; ++d) {
            float4 nw, m01, m23, m45, m67;
            if (d < 3) {   // prefetch next double-step
                nw = pload(ebase, half, wr[2*d + 6], wr[2*d + 7]);
                const int4 pa = *(const int4*)(nr + 8*(d + 1));
                const int4 pb = *(const int4*)(nr + 8*(d + 1) + 4);
                m01 = pload(ebase, half, pa.x, pa.y);
                m23 = pload(ebase, half, pa.z, pa.w);
                m45 = pload(ebase, half, pb.x, pb.y);
                m67 = pload(ebase, half, pb.z, pb.w);
            } else {
                // tail prefetch: window row 22 (wr[12] is the LAST walk element
                // at b=1023,chunk=3 — row 23 is never touched) + tail anchor negs.
                const int i22 = wr[12];
                nw = pload(ebase, half, i22, i22);
                const int4 pa = *(const int4*)(nr + 32);   // nrow+72: anchor 18 negs
                m01 = pload(ebase, half, pa.x, pa.y);
                m23 = pload(ebase, half, pa.z, pa.w);
                m45 = m01;  m67 = m23;   // unused in tail; keep defined
            }
            dstep(w01, w23, w45, n01, n23, n45, n67);
            w01 = w23;  w23 = w45;  w45 = nw;
            n01 = m01;  n23 = m23;  n45 = m45;  n67 = m67;
        }

        // tail anchor (local row 18): w01=rows(18,19), w23=(20,21), w45=(22,22)
        {
            const float4 Y   = swap32(w01);
            const float4 Z0  = sel4(half, Y, w01);      // anchor 18's frag
            const float4 Aop = sel4(half, w01, w23);    // pos row (19 | 20)
            const float4 Bop = sel4(half, w23, w45);    // pos row (21 | 22)

            const float t0 = dot4(Z0, Aop);
            const float t1 = dot4(Z0, Bop);
            const float t2 = dot4(Z0, n01);
            const float t3 = dot4(Z0, n23);

            float u0 = (hi1 ? t2 : t0) + __shfl_xor(hi1 ? t0 : t2, 1);
            float u1 = (hi1 ? t3 : t1) + __shfl_xor(hi1 ? t1 : t3, 1);
            float v  = (hi2 ? u1 : u0) + __shfl_xor(hi2 ? u0 : u1, 2);
            v += __shfl_xor(v, 4);
            v += __shfl_xor(v, 8);
            v += __shfl_xor(v, 16);
            tsum = softplus(hi1 ? v : -v);              // 8x replicated per half
        }
    }

    // double-step logits counted 4x, tail logits 8x -> normalize to 1x
    float tot = wsum + 0.5f * tsum;
    #pragma unroll
    for (int m = 1; m < 64; m <<= 1) tot += __shfl_xor(tot, m);

    if (lane == 0) s_wsum[wave] = tot * 0.25f;
    __syncthreads();
    if (tid == 0)
        ws[blockIdx.x] = s_wsum[0] + s_wsum[1];
}

__global__ __launch_bounds__(256) void sg_reduce(
    const float* __restrict__ ws, float* __restrict__ out)
{
    __shared__ float s[4];
    const int tid = threadIdx.x;
    float sum = 0.0f;
    #pragma unroll
    for (int i = 0; i < NBLOCKS / 256; ++i) sum += ws[tid + i * 256];
    #pragma unroll
    for (int m = 1; m < 64; m <<= 1) sum += __shfl_xor(sum, m);
    const int wave = tid >> 6;
    const int lane = tid & 63;
    if (lane == 0) s[wave] = sum;
    __syncthreads();
    if (tid == 0) {
        const float total = (float)((size_t)PAIRS * 8);   // 622592 logits
        out[0] = (s[0] + s[1] + s[2] + s[3]) * (1.0f / total);
    }
}

extern "C" void kernel_launch(void* const* d_in, const int* in_sizes, int n_in,
                              void* d_out, int out_size, void* d_ws, size_t ws_size,
                              hipStream_t stream) {
    const int*   walk  = (const int*)d_in[0];
    const int*   neg   = (const int*)d_in[1];
    const float* embed = (const float*)d_in[2];
    float* ws  = (float*)d_ws;   // NBLOCKS floats of scratch (16 KB)
    float* out = (float*)d_out;

    sg_partial<<<NBLOCKS, 128, 0, stream>>>(walk, neg, embed, ws);
    sg_reduce<<<1, 256, 0, stream>>>(ws, out);
}